// Round 8
// baseline (147.625 us; speedup 1.0000x reference)
//
#include <hip/hip_runtime.h>

typedef __bf16 bf16_t;
typedef bf16_t bf16x2 __attribute__((ext_vector_type(2)));
typedef bf16_t bf16x8 __attribute__((ext_vector_type(8)));
typedef float  floatx16 __attribute__((ext_vector_type(16)));
typedef unsigned int uintx4 __attribute__((ext_vector_type(4)));

constexpr int Sq = 2048, Dq = 64;
constexpr int BQ = 64;            // q-tile per block (2 q-halves x 32 rows)
constexpr int KVB = 32;           // kv sub-tile per group per slot
constexpr int NQT = Sq / BQ;      // 32
constexpr float SCALE_LOG2E = 0.125f * 1.44269504088896340736f;
constexpr int KROW_B = 128;       // K LDS row bytes (64 bf16), XOR-swizzled
constexpr int VROW_B = 80;        // V^T LDS row bytes (32 bf16 + pad -> 20-bank stride)

// R8 = R7 resubmitted (R7 bench was an infra failure, no data).
// Theory: R3's wall is LDS *bandwidth* (~96KB/block-iter: 4-wave K/V frag
// amplification + P round-trip + staging ~= 70% of the 128B/cy pipe), not
// barriers (R1: more blocks null) and not slot count (R4/R6 regressions were
// residency collapses at 55/64KB LDS).
// This kernel: R6's verified 32x32 swapped-QK core (identical P-pack code) in
// R3's verified residency wrapper. 256t/4 waves, wave = (grp = kv-parity
// split-K) x (qh = 32 q-rows). Per unit work LDS: K frags 2x (not 4x), V
// frags 2x, P = 0 (in-register cvt_pk+permlane pack), staging same -> 48KB
// per 64q-tile-unit. LDS/block = 36.9KB -> 2 blocks/CU everywhere.
// Pair {pr,31-pr} -> exactly 33 uniform slots/block, both groups busy at
// every slot. Split-K combine once per q-tile through the LDS union.
// XCD affinity: id%8 = bh%8.
struct LoopS { char Kl[2][2][KVB * KROW_B]; char Vl[2][2][Dq * VROW_B]; }; // 36864B
struct EpiS  { float Op[BQ][Dq]; float den[BQ]; };                        // 16640B
union  SmemU { LoopS l; EpiS e; };

static __device__ __forceinline__ bf16x8 cvt8(const float4& a, const float4& b) {
    bf16x8 w;
    w[0] = (bf16_t)a.x; w[1] = (bf16_t)a.y; w[2] = (bf16_t)a.z; w[3] = (bf16_t)a.w;
    w[4] = (bf16_t)b.x; w[5] = (bf16_t)b.y; w[6] = (bf16_t)b.z; w[7] = (bf16_t)b.w;
    return w;
}
static __device__ __forceinline__ bf16x8 cvt8s(const float4& a, const float4& b) {
    bf16x8 w;
    w[0] = (bf16_t)(a.x * SCALE_LOG2E); w[1] = (bf16_t)(a.y * SCALE_LOG2E);
    w[2] = (bf16_t)(a.z * SCALE_LOG2E); w[3] = (bf16_t)(a.w * SCALE_LOG2E);
    w[4] = (bf16_t)(b.x * SCALE_LOG2E); w[5] = (bf16_t)(b.y * SCALE_LOG2E);
    w[6] = (bf16_t)(b.z * SCALE_LOG2E); w[7] = (bf16_t)(b.w * SCALE_LOG2E);
    return w;
}
static __device__ __forceinline__ unsigned int pkbf(float lo, float hi) {
    bf16x2 t; t[0] = (bf16_t)lo; t[1] = (bf16_t)hi;
    return __builtin_bit_cast(unsigned int, t);
}

#define SUM16(p) (((((p)[0]+(p)[1])+((p)[2]+(p)[3]))+(((p)[4]+(p)[5])+((p)[6]+(p)[7]))) \
                + ((((p)[8]+(p)[9])+((p)[10]+(p)[11]))+(((p)[12]+(p)[13])+((p)[14]+(p)[15]))))

// issue next-tile global loads (consumed by WRITEKV one compute-phase later)
#define LOADKV(TG) do {                                                        \
    const long kb_ = base + (long)(TG) * KVB * Dq;                             \
    const float* kp_ = &K[kb_ + (long)krow_l * Dq + kc0];                      \
    kr0 = *(const float4*)&kp_[0];  kr1 = *(const float4*)&kp_[4];             \
    kr2 = *(const float4*)&kp_[8];  kr3 = *(const float4*)&kp_[12];            \
    const float* vp_ = &V[kb_ + (long)(16 * vkh) * Dq + vd];                   \
    _Pragma("unroll")                                                          \
    for (int m_ = 0; m_ < 16; ++m_) vraw[m_] = vp_[m_ * Dq];                   \
} while (0)

// cvt + LDS write (K XOR-swizzled rows; V^T pad-80 rows)
#define WRITEKV(BUF) do {                                                      \
    char* kc_ = &sm.l.Kl[grp][BUF][krow_l * KROW_B];                           \
    const int ksw_ = (krow_l & 7) << 4;                                        \
    *(bf16x8*)(kc_ + ((2 * kc0) ^ ksw_))      = cvt8(kr0, kr1);                \
    *(bf16x8*)(kc_ + ((2 * kc0 + 16) ^ ksw_)) = cvt8(kr2, kr3);                \
    char* vc_ = &sm.l.Vl[grp][BUF][vd * VROW_B + 32 * vkh];                    \
    bf16x8 v0_, v1_;                                                           \
    _Pragma("unroll")                                                          \
    for (int m_ = 0; m_ < 8; ++m_) {                                           \
        v0_[m_] = (bf16_t)vraw[m_]; v1_[m_] = (bf16_t)vraw[8 + m_];            \
    }                                                                          \
    *(bf16x8*)(vc_)      = v0_;                                                \
    *(bf16x8*)(vc_ + 16) = v1_;                                                \
} while (0)

__global__ __launch_bounds__(256, 2) void flash_attn_kernel(
    const float* __restrict__ Q, const float* __restrict__ K,
    const float* __restrict__ V, float* __restrict__ O)
{
    __shared__ SmemU sm;

    const int tid  = threadIdx.x;
    const int wave = tid >> 6;
    const int lane = tid & 63;
    const int hi   = lane >> 5;
    const int l31  = lane & 31;
    const int grp  = wave >> 1;         // kv-parity split-K group
    const int qh   = wave & 1;          // q-half (32 rows)

    const int id = blockIdx.x;
    const int bh = (id & 7) + ((id >> 7) << 3);
    const int pr = (id >> 3) & 15;      // pair {pr, 31-pr}
    const long base = (long)bh * Sq * Dq;

    // staging ids (within this group's 128 threads)
    const int gt     = tid & 127;
    const int krow_l = gt >> 2;         // K: 0..31, 4 threads/row
    const int kc0    = (gt & 3) * 16;   // K: col base (floats)
    const int vd     = gt >> 1;         // V: d-row 0..63, 2 threads/row
    const int vkh    = gt & 1;          // V: k-half

    for (int half = 0; half < 2; ++half) {
        const int qt = half ? (NQT - 1 - pr) : pr;
        const long qb = base + (long)qt * BQ * Dq;

        // ---- Q fragments (B-operand of S^T = K*Q^T), scaled ----
        bf16x8 qf0, qf1, qf2, qf3;
        {
            const float* qp = &Q[qb + (long)(32 * qh + l31) * Dq + 8 * hi];
            qf0 = cvt8s(*(const float4*)&qp[0],  *(const float4*)&qp[4]);
            qf1 = cvt8s(*(const float4*)&qp[16], *(const float4*)&qp[20]);
            qf2 = cvt8s(*(const float4*)&qp[32], *(const float4*)&qp[36]);
            qf3 = cvt8s(*(const float4*)&qp[48], *(const float4*)&qp[52]);
        }

        float4 kr0, kr1, kr2, kr3;
        float  vraw[16];
        float  l_lane = 0.f;
        floatx16 oacc0 = (floatx16)0.f, oacc1 = (floatx16)0.f;

        __syncthreads();            // prior half's epilogue LDS reads done
        LOADKV(grp);                // slot-0 tile: grp0 -> 0, grp1 -> 1
        WRITEKV(0);
        __syncthreads();            // buf0 ready

        for (int s = 0; s <= qt; ++s) {
            const int buf = s & 1;
            const bool more = (s < qt);
            if (more) LOADKV(2 * (s + 1) + grp);   // always a valid tile

            const int tg = 2 * s + grp;
            // skip only the fully-masked case (grp1, qh0, s==qt)
            if (32 * tg <= 64 * qt + 32 * qh + 31) {
                const char* kb_ = &sm.l.Kl[grp][buf][l31 * KROW_B];
                const int lsw = (l31 & 7) << 4;

                // ---- S^T = K * Q^T (one 32x32 acc, 4 chained mfma) ----
                floatx16 s0 = (floatx16)0.f;
                __builtin_amdgcn_s_setprio(1);
                s0 = __builtin_amdgcn_mfma_f32_32x32x16_bf16(
                         *(const bf16x8*)(kb_ + ((16 * hi) ^ lsw)),      qf0, s0, 0, 0, 0);
                s0 = __builtin_amdgcn_mfma_f32_32x32x16_bf16(
                         *(const bf16x8*)(kb_ + ((32 + 16 * hi) ^ lsw)), qf1, s0, 0, 0, 0);
                s0 = __builtin_amdgcn_mfma_f32_32x32x16_bf16(
                         *(const bf16x8*)(kb_ + ((64 + 16 * hi) ^ lsw)), qf2, s0, 0, 0, 0);
                s0 = __builtin_amdgcn_mfma_f32_32x32x16_bf16(
                         *(const bf16x8*)(kb_ + ((96 + 16 * hi) ^ lsw)), qf3, s0, 0, 0, 0);
                __builtin_amdgcn_s_setprio(0);

                // ---- mask + p = 2^s + denom (in-register) ----
                float p0[16];
                const bool diag = (tg == 2 * qt + qh);
                #pragma unroll
                for (int r = 0; r < 16; ++r) {
                    const int cr = (r & 3) + 8 * (r >> 2) + 4 * hi;   // k row
                    float a = s0[r];
                    if (diag && (32 * tg + cr > 64 * qt + 32 * qh + l31)) a = -1e30f;
                    p0[r] = __builtin_amdgcn_exp2f(a);
                }
                l_lane += SUM16(p0);

                // ---- P -> PV A-frags: cvt_pk pairs + permlane32_swap (T12) ----
                unsigned int w00, w01, w02, w03, w10, w11, w12, w13;
                {
                    unsigned int c0 = pkbf(p0[0], p0[1]), c1 = pkbf(p0[2], p0[3]);
                    unsigned int d0 = pkbf(p0[4], p0[5]), d1 = pkbf(p0[6], p0[7]);
                    asm volatile("v_permlane32_swap_b32 %0, %1" : "+v"(c0), "+v"(d0));
                    asm volatile("v_permlane32_swap_b32 %0, %1" : "+v"(c1), "+v"(d1));
                    w00 = c0; w01 = c1; w02 = d0; w03 = d1;
                }
                {
                    unsigned int c0 = pkbf(p0[8], p0[9]),   c1 = pkbf(p0[10], p0[11]);
                    unsigned int d0 = pkbf(p0[12], p0[13]), d1 = pkbf(p0[14], p0[15]);
                    asm volatile("v_permlane32_swap_b32 %0, %1" : "+v"(c0), "+v"(d0));
                    asm volatile("v_permlane32_swap_b32 %0, %1" : "+v"(c1), "+v"(d1));
                    w10 = c0; w11 = c1; w12 = d0; w13 = d1;
                }
                uintx4 f0; f0[0] = w00; f0[1] = w01; f0[2] = w02; f0[3] = w03;
                uintx4 f1; f1[0] = w10; f1[1] = w11; f1[2] = w12; f1[3] = w13;
                const bf16x8 pa0 = __builtin_bit_cast(bf16x8, f0);
                const bf16x8 pa1 = __builtin_bit_cast(bf16x8, f1);

                // ---- O += P V  (B = V^T rows = d, pad-80 layout) ----
                const char* vb_ = &sm.l.Vl[grp][buf][0];
                const char* vr0 = vb_ + l31 * VROW_B + 16 * hi;
                const char* vr1 = vb_ + (32 + l31) * VROW_B + 16 * hi;
                __builtin_amdgcn_s_setprio(1);
                oacc0 = __builtin_amdgcn_mfma_f32_32x32x16_bf16(
                            pa0, *(const bf16x8*)(vr0),      oacc0, 0, 0, 0);
                oacc0 = __builtin_amdgcn_mfma_f32_32x32x16_bf16(
                            pa1, *(const bf16x8*)(vr0 + 32), oacc0, 0, 0, 0);
                oacc1 = __builtin_amdgcn_mfma_f32_32x32x16_bf16(
                            pa0, *(const bf16x8*)(vr1),      oacc1, 0, 0, 0);
                oacc1 = __builtin_amdgcn_mfma_f32_32x32x16_bf16(
                            pa1, *(const bf16x8*)(vr1 + 32), oacc1, 0, 0, 0);
                __builtin_amdgcn_s_setprio(0);
            }

            if (more) WRITEKV(buf ^ 1);     // loads had full compute phase in flight
            __syncthreads();
        }

        // ---- split-K combine (once per q-tile), divide, store ----
        const float lden = l_lane + __shfl_xor(l_lane, 32);

        if (grp == 1) {
            #pragma unroll
            for (int r = 0; r < 16; ++r) {
                const int cr = (r & 3) + 8 * (r >> 2) + 4 * hi;
                sm.e.Op[32 * qh + cr][l31]      = oacc0[r];
                sm.e.Op[32 * qh + cr][32 + l31] = oacc1[r];
            }
            if (hi == 0) sm.e.den[32 * qh + l31] = lden;
        }
        __syncthreads();
        if (grp == 0) {
            #pragma unroll
            for (int r = 0; r < 16; ++r) {
                const int cr = (r & 3) + 8 * (r >> 2) + 4 * hi;
                const float dA = __shfl(lden, cr);            // own (even-tile) denom
                const float dB = sm.e.den[32 * qh + cr];      // odd-tile denom
                const float inv = 1.f / (dA + dB);
                const long orow = qb + (long)(32 * qh + cr) * Dq;
                O[orow + l31]      = (oacc0[r] + sm.e.Op[32 * qh + cr][l31]) * inv;
                O[orow + 32 + l31] = (oacc1[r] + sm.e.Op[32 * qh + cr][32 + l31]) * inv;
            }
        }
        // next half's first __syncthreads protects LDS reuse
    }
}

extern "C" void kernel_launch(void* const* d_in, const int* in_sizes, int n_in,
                              void* d_out, int out_size, void* d_ws, size_t ws_size,
                              hipStream_t stream)
{
    const float* q = (const float*)d_in[0];
    const float* k = (const float*)d_in[1];
    const float* v = (const float*)d_in[2];
    float* out = (float*)d_out;
    // d_in[3] (mask) is the static causal mask; handled analytically in-kernel.
    flash_attn_kernel<<<dim3(512, 1, 1), dim3(256, 1, 1), 0, stream>>>(q, k, v, out);
}